// Round 4
// baseline (90.221 us; speedup 1.0000x reference)
//
#include <hip/hip_runtime.h>
#include <hip/hip_bf16.h>
#include <math.h>

#define EMBED  768
#define SEQ    4096
#define ADIM   64
#define NBATCH 4
#define WELEMS (ADIM * EMBED)          // 49152 per matrix
#define QSCALE (0.125f * 1.44269504088896340736f)

typedef __bf16 bf16;
typedef unsigned int u32;
typedef __attribute__((ext_vector_type(8))) __bf16 bf16x8;
typedef __attribute__((ext_vector_type(4))) __bf16 bf16x4;
typedef __attribute__((ext_vector_type(4))) float f32x4;
typedef __attribute__((ext_vector_type(16))) float f32x16;

__device__ __forceinline__ f32x4 mfma16(bf16x8 a, bf16x8 b, f32x4 c) {
  return __builtin_amdgcn_mfma_f32_16x16x32_bf16(a, b, c, 0, 0, 0);
}
__device__ __forceinline__ f32x16 mfma32(bf16x8 a, bf16x8 b, f32x16 c) {
  return __builtin_amdgcn_mfma_f32_32x32x16_bf16(a, b, c, 0, 0, 0);
}
__device__ __forceinline__ unsigned cvtpk(float lo, float hi) {
  unsigned d;
  asm("v_cvt_pk_bf16_f32 %0, %1, %2" : "=v"(d) : "v"(lo), "v"(hi));
  return d;
}
// async 16B-per-lane global -> LDS DMA (lane i lands at ldsbase + i*16B)
__device__ __forceinline__ void gl_lds16(const bf16* g, bf16* l) {
  __builtin_amdgcn_global_load_lds(
      (const __attribute__((address_space(1))) u32*)g,
      (__attribute__((address_space(3))) u32*)l, 16, 0, 0);
}

// ---------------------------------------------------------------------------
// W fp32 -> bf16 once (Q-scale folded into Wq). Wb = [3][ADIM][EMBED] bf16.
// ---------------------------------------------------------------------------
__global__ __launch_bounds__(256) void wconv_kernel(
    const float* __restrict__ Wq, const float* __restrict__ Wk,
    const float* __restrict__ Wv, bf16* __restrict__ Wb)
{
  const int gid = blockIdx.x * 256 + threadIdx.x;
  const int m   = gid / (WELEMS / 4);
  const int off = (gid % (WELEMS / 4)) * 4;
  const float* src = (m == 0) ? Wq : ((m == 1) ? Wk : Wv);
  const float  sc  = (m == 0) ? QSCALE : 1.0f;
  float4 v = *reinterpret_cast<const float4*>(src + off);
  bf16x4 o;
  o[0] = (bf16)(v.x * sc); o[1] = (bf16)(v.y * sc);
  o[2] = (bf16)(v.z * sc); o[3] = (bf16)(v.w * sc);
  *reinterpret_cast<bf16x4*>(Wb + (size_t)m * WELEMS + off) = o;
}

// ---------------------------------------------------------------------------
// Projection: Y = X @ W^T for all 3 W. X A-fragments loaded straight from
// global (no LDS round-trip); W staged via global_load_lds DMA into unpadded
// [192][32] bf16 (64B rows -> each 16-row fragment tile is 1KB contiguous,
// conflict-free ds_read_b128). Double-buffered, one barrier per K-step.
// ---------------------------------------------------------------------------
__global__ __launch_bounds__(256) void proj_kernel(
    const float* __restrict__ x, const bf16* __restrict__ Wb,
    bf16* __restrict__ Qs, bf16* __restrict__ Ks, bf16* __restrict__ Vt)
{
  __shared__ bf16 Ws[2][192][32];

  const int t    = threadIdx.x;
  const int lane = t & 63;
  const int w    = t >> 6;
  const int r    = lane & 15;
  const int g    = lane >> 4;
  const long long row0 = (long long)blockIdx.x * 64;

  f32x4 acc[12];
  #pragma unroll
  for (int i = 0; i < 12; ++i) acc[i] = f32x4{0.f, 0.f, 0.f, 0.f};

  // per-lane X source: row = row0 + w*16 + r, col chunk g*8
  const float* xsrc = x + (row0 + w * 16 + r) * EMBED + g * 8;
  // per-lane W DMA source pattern: 4 lanes per row, (lane&3)*8 col offset
  const bf16* wdma = Wb + (long long)(lane >> 2) * EMBED + (lane & 3) * 8;

  // stage W tile for k0 into buffer buf: wave w stages rows [48w, 48w+48)
  #define STAGE_W(k0, buf)                                                   \
    {                                                                        \
      _Pragma("unroll")                                                      \
      for (int c = 0; c < 3; ++c) {                                          \
        const int n0 = 48 * w + 16 * c;                                      \
        gl_lds16(wdma + (long long)n0 * EMBED + (k0), &Ws[buf][n0][0]);      \
      }                                                                      \
    }

  // prologue
  STAGE_W(0, 0);
  float4 xa = *reinterpret_cast<const float4*>(xsrc);
  float4 xb = *reinterpret_cast<const float4*>(xsrc + 4);
  __syncthreads();   // drains DMA (vmcnt0 before barrier)

  int cur = 0;
  for (int kt = 0; kt < 24; ++kt) {
    float4 xa2, xb2;
    const bool pf = kt < 23;
    if (pf) {
      const int k0n = (kt + 1) * 32;
      STAGE_W(k0n, cur ^ 1);
      xa2 = *reinterpret_cast<const float4*>(xsrc + k0n);
      xb2 = *reinterpret_cast<const float4*>(xsrc + k0n + 4);
    }
    bf16x8 af;
    af[0]=(bf16)xa.x; af[1]=(bf16)xa.y; af[2]=(bf16)xa.z; af[3]=(bf16)xa.w;
    af[4]=(bf16)xb.x; af[5]=(bf16)xb.y; af[6]=(bf16)xb.z; af[7]=(bf16)xb.w;
    #pragma unroll
    for (int n = 0; n < 12; ++n) {
      bf16x8 bfrag = *reinterpret_cast<const bf16x8*>(&Ws[cur][n * 16 + r][g * 8]);
      acc[n] = mfma16(af, bfrag, acc[n]);
    }
    __syncthreads();   // waves done reading cur; next DMA + X loads complete
    if (pf) { xa = xa2; xb = xb2; }
    cur ^= 1;
  }
  #undef STAGE_W

  // epilogue: 16x16 D layout row=(g*4+j), col=r (Q scale folded into Wq)
  const long long rowbase = row0 + w * 16 + g * 4;
  #pragma unroll
  for (int n = 0; n < 4; ++n) {
    #pragma unroll
    for (int j = 0; j < 4; ++j) {
      Qs[(rowbase + j) * ADIM + n * 16 + r] = (bf16)(acc[n][j]);
      Ks[(rowbase + j) * ADIM + n * 16 + r] = (bf16)(acc[4 + n][j]);
    }
  }
  const int bb = (int)(rowbase >> 12);
  const int ss = (int)(rowbase & 4095);
  #pragma unroll
  for (int n = 0; n < 4; ++n) {
    const int d = n * 16 + r;
    bf16x4 pack;
    pack[0] = (bf16)(acc[8 + n][0]);
    pack[1] = (bf16)(acc[8 + n][1]);
    pack[2] = (bf16)(acc[8 + n][2]);
    pack[3] = (bf16)(acc[8 + n][3]);
    *reinterpret_cast<bf16x4*>(&Vt[((long long)bb * 64 + d) * SEQ + ss]) = pack;
  }
}

// ---------------------------------------------------------------------------
// Flash attention, causal. 32x32x16 MFMA, swapped operands: q = lane&31.
// 512 blocks x 8 waves; block owns one 32-row q-tile; waves kv-split stride 8.
// Adjacent blocks pair (qt, 127-qt) so each CU's 2 resident blocks balance.
// ---------------------------------------------------------------------------
__global__ __launch_bounds__(512, 4) void attn_kernel(
    const bf16* __restrict__ Qs, const bf16* __restrict__ Ks,
    const bf16* __restrict__ Vt, float* __restrict__ out)
{
  __shared__ float Olds[8][32][68];
  __shared__ float Mlds[8][32];
  __shared__ float Llds[8][32];

  const int t    = threadIdx.x;
  const int lane = t & 63;
  const int w    = t >> 6;
  const int q    = lane & 31;
  const int h    = lane >> 5;
  const int bi   = blockIdx.x;
  const int j_   = bi >> 1;
  const int b    = j_ >> 6;
  const int jj   = j_ & 63;
  const int qt   = (bi & 1) ? (127 - jj) : jj;
  const int qb   = qt * 32;

  const bf16* Qb = Qs + (long long)b * SEQ * ADIM;
  const bf16* Kb = Ks + (long long)b * SEQ * ADIM;
  const bf16* Vb = Vt + (long long)b * ADIM * SEQ;

  // Q as B-operand: lane(q,h) holds Q[qb+q][kc*16 + h*8 + e]
  bf16x8 qf[4];
  #pragma unroll
  for (int kc = 0; kc < 4; ++kc)
    qf[kc] = *reinterpret_cast<const bf16x8*>(Qb + (qb + q) * ADIM + kc * 16 + h * 8);

  f32x16 o0 = {0,0,0,0,0,0,0,0,0,0,0,0,0,0,0,0};
  f32x16 o1 = {0,0,0,0,0,0,0,0,0,0,0,0,0,0,0,0};
  float m = -INFINITY, l = 0.f;

  const bf16* krow  = Kb + q * ADIM + h * 8;
  const bf16* vrow0 = Vb + (long long)q * SEQ + h * 8;
  const bf16* vrow1 = Vb + (long long)(32 + q) * SEQ + h * 8;

  int st = w;
  bf16x8 kf[4];
  if (st <= qt) {
    #pragma unroll
    for (int kc = 0; kc < 4; ++kc)
      kf[kc] = *reinterpret_cast<const bf16x8*>(krow + st * 32 * ADIM + kc * 16);
  }

  for (; st <= qt; st += 8) {
    const int kv0 = st * 32;

    // V for this tile (in flight across QK + softmax)
    bf16x8 vf00 = *reinterpret_cast<const bf16x8*>(vrow0 + kv0);
    bf16x8 vf01 = *reinterpret_cast<const bf16x8*>(vrow0 + kv0 + 16);
    bf16x8 vf10 = *reinterpret_cast<const bf16x8*>(vrow1 + kv0);
    bf16x8 vf11 = *reinterpret_cast<const bf16x8*>(vrow1 + kv0 + 16);

    // S^T = K Q^T : lane(q,h) reg(i*4+j) = S[key=kv0+j+8i+4h][qb+q]
    f32x16 s = {0,0,0,0,0,0,0,0,0,0,0,0,0,0,0,0};
    __builtin_amdgcn_s_setprio(1);
    s = mfma32(kf[0], qf[0], s);
    s = mfma32(kf[1], qf[1], s);
    s = mfma32(kf[2], qf[2], s);
    s = mfma32(kf[3], qf[3], s);
    __builtin_amdgcn_s_setprio(0);

    // prefetch next K tile (in flight across softmax + PV)
    if (st + 8 <= qt) {
      #pragma unroll
      for (int kc = 0; kc < 4; ++kc)
        kf[kc] = *reinterpret_cast<const bf16x8*>(krow + (st + 8) * 32 * ADIM + kc * 16);
    }

    // causal mask — only the diagonal tile
    if (st == qt) {
      #pragma unroll
      for (int i = 0; i < 4; ++i)
        #pragma unroll
        for (int j = 0; j < 4; ++j)
          if (kv0 + j + 8 * i + 4 * h > qb + q) s[i * 4 + j] = -INFINITY;
    }

    // per-lane online softmax: 1 shuffle for max, 1 for sum
    float tm = s[0];
    #pragma unroll
    for (int rr = 1; rr < 16; ++rr) tm = fmaxf(tm, s[rr]);
    tm = fmaxf(tm, __shfl_xor(tm, 32));

    const bool skip = __all((m > -1e37f) && (tm <= m + 8.0f));  // defer-max
    float mne;
    if (skip) {
      mne = m;
    } else {
      const float mn = fmaxf(m, tm);
      mne = (mn == -INFINITY) ? 0.f : mn;
      const float sc = exp2f(m - mne);
      #pragma unroll
      for (int rr = 0; rr < 16; ++rr) { o0[rr] *= sc; o1[rr] *= sc; }
      l *= sc;
      m = mn;
    }

    float rs = 0.f;
    #pragma unroll
    for (int rr = 0; rr < 16; ++rr) { s[rr] = exp2f(s[rr] - mne); rs += s[rr]; }
    rs += __shfl_xor(rs, 32);
    l += rs;

    // P^T fragments in-register, built in two halves (register relief):
    // half 0: keys kv0+0..15 (s[0..7]) -> pa0, feed 2 PV MFMAs
    {
      unsigned a0 = cvtpk(s[0], s[1]), a1 = cvtpk(s[2], s[3]);
      unsigned b0 = cvtpk(s[4], s[5]), b1 = cvtpk(s[6], s[7]);
      unsigned a0x = __shfl_xor((int)a0, 32), a1x = __shfl_xor((int)a1, 32);
      unsigned b0x = __shfl_xor((int)b0, 32), b1x = __shfl_xor((int)b1, 32);
      union { unsigned u[4]; bf16x8 v; } pa0;
      pa0.u[0] = h ? b0x : a0;  pa0.u[1] = h ? b1x : a1;
      pa0.u[2] = h ? b0  : a0x; pa0.u[3] = h ? b1  : a1x;
      __builtin_amdgcn_s_setprio(1);
      o0 = mfma32(vf00, pa0.v, o0);
      o1 = mfma32(vf10, pa0.v, o1);
      __builtin_amdgcn_s_setprio(0);
    }
    // half 1: keys kv0+16..31 (s[8..15]) -> pa1, feed 2 PV MFMAs
    {
      unsigned c0 = cvtpk(s[8],  s[9]),  c1 = cvtpk(s[10], s[11]);
      unsigned d0 = cvtpk(s[12], s[13]), d1 = cvtpk(s[14], s[15]);
      unsigned c0x = __shfl_xor((int)c0, 32), c1x = __shfl_xor((int)c1, 32);
      unsigned d0x = __shfl_xor((int)d0, 32), d1x = __shfl_xor((int)d1, 32);
      union { unsigned u[4]; bf16x8 v; } pa1;
      pa1.u[0] = h ? d0x : c0;  pa1.u[1] = h ? d1x : c1;
      pa1.u[2] = h ? d0  : c0x; pa1.u[3] = h ? d1  : c1x;
      __builtin_amdgcn_s_setprio(1);
      o0 = mfma32(vf01, pa1.v, o0);
      o1 = mfma32(vf11, pa1.v, o1);
      __builtin_amdgcn_s_setprio(0);
    }
  }

  // publish partials (C/D layout: d = dc*32 + 8*r2 + 4*h + j)
  #pragma unroll
  for (int r2 = 0; r2 < 4; ++r2) {
    f32x4 v0, v1;
    v0[0]=o0[r2*4+0]; v0[1]=o0[r2*4+1]; v0[2]=o0[r2*4+2]; v0[3]=o0[r2*4+3];
    v1[0]=o1[r2*4+0]; v1[1]=o1[r2*4+1]; v1[2]=o1[r2*4+2]; v1[3]=o1[r2*4+3];
    *reinterpret_cast<f32x4*>(&Olds[w][q][8 * r2 + 4 * h])      = v0;
    *reinterpret_cast<f32x4*>(&Olds[w][q][32 + 8 * r2 + 4 * h]) = v1;
  }
  if (h == 0) { Mlds[w][q] = m; Llds[w][q] = l; }
  __syncthreads();

  // combine 8 partials: thread -> (q=t>>4, 4 dims at (t&15)*4)
  {
    const int cq = t >> 4;
    const int cd = (t & 15) * 4;
    float mf = Mlds[0][cq];
    #pragma unroll
    for (int w2 = 1; w2 < 8; ++w2) mf = fmaxf(mf, Mlds[w2][cq]);
    float lf = 0.f;
    f32x4 ov = {0.f, 0.f, 0.f, 0.f};
    #pragma unroll
    for (int w2 = 0; w2 < 8; ++w2) {
      const float sc = exp2f(Mlds[w2][cq] - mf);
      lf += sc * Llds[w2][cq];
      const f32x4 pv = *reinterpret_cast<const f32x4*>(&Olds[w2][cq][cd]);
      ov[0] += sc * pv[0]; ov[1] += sc * pv[1];
      ov[2] += sc * pv[2]; ov[3] += sc * pv[3];
    }
    const float inv = 1.f / lf;
    float4 res;
    res.x = ov[0] * inv; res.y = ov[1] * inv;
    res.z = ov[2] * inv; res.w = ov[3] * inv;
    *reinterpret_cast<float4*>(out + ((long long)b * SEQ + qb + cq) * ADIM + cd) = res;
  }
}

extern "C" void kernel_launch(void* const* d_in, const int* in_sizes, int n_in,
                              void* d_out, int out_size, void* d_ws, size_t ws_size,
                              hipStream_t stream) {
  const float* x  = (const float*)d_in[0];
  const float* Wq = (const float*)d_in[1];
  const float* Wk = (const float*)d_in[2];
  const float* Wv = (const float*)d_in[3];

  const size_t qkvElems = (size_t)NBATCH * SEQ * ADIM;
  bf16* Qs = (bf16*)d_ws;
  bf16* Ks = Qs + qkvElems;
  bf16* Vt = Ks + qkvElems;
  bf16* Wb = Vt + qkvElems;

  wconv_kernel<<<3 * WELEMS / 4 / 256, 256, 0, stream>>>(Wq, Wk, Wv, Wb);
  proj_kernel<<<NBATCH * SEQ / 64, 256, 0, stream>>>(x, Wb, Qs, Ks, Vt);
  attn_kernel<<<512, 512, 0, stream>>>(Qs, Ks, Vt, (float*)d_out);
}

// Round 5
// 68.700 us; speedup vs baseline: 1.3133x; 1.3133x over previous
//
#include <hip/hip_runtime.h>
#include <hip/hip_bf16.h>
#include <math.h>

#define EMBED  768
#define SEQ    4096
#define ADIM   64
#define NBATCH 4
#define WELEMS (ADIM * EMBED)          // 49152 per matrix
#define QSCALE (0.125f * 1.44269504088896340736f)

typedef __bf16 bf16;
typedef unsigned int u32;
typedef __attribute__((ext_vector_type(8))) __bf16 bf16x8;
typedef __attribute__((ext_vector_type(4))) __bf16 bf16x4;
typedef __attribute__((ext_vector_type(4))) float f32x4;
typedef __attribute__((ext_vector_type(16))) float f32x16;

__device__ __forceinline__ f32x4 mfma16(bf16x8 a, bf16x8 b, f32x4 c) {
  return __builtin_amdgcn_mfma_f32_16x16x32_bf16(a, b, c, 0, 0, 0);
}
__device__ __forceinline__ f32x16 mfma32(bf16x8 a, bf16x8 b, f32x16 c) {
  return __builtin_amdgcn_mfma_f32_32x32x16_bf16(a, b, c, 0, 0, 0);
}
__device__ __forceinline__ unsigned cvtpk(float lo, float hi) {
  unsigned d;
  asm("v_cvt_pk_bf16_f32 %0, %1, %2" : "=v"(d) : "v"(lo), "v"(hi));
  return d;
}
// async 16B-per-lane global -> LDS DMA (lane i lands at ldsbase + i*16B)
__device__ __forceinline__ void gl_lds16(const bf16* g, bf16* l) {
  __builtin_amdgcn_global_load_lds(
      (const __attribute__((address_space(1))) u32*)g,
      (__attribute__((address_space(3))) u32*)l, 16, 0, 0);
}

// ---------------------------------------------------------------------------
// W fp32 -> bf16 once (Q-scale folded into Wq). Wb = [3][ADIM][EMBED] bf16.
// ---------------------------------------------------------------------------
__global__ __launch_bounds__(256) void wconv_kernel(
    const float* __restrict__ Wq, const float* __restrict__ Wk,
    const float* __restrict__ Wv, bf16* __restrict__ Wb)
{
  const int gid = blockIdx.x * 256 + threadIdx.x;
  const int m   = gid / (WELEMS / 4);
  const int off = (gid % (WELEMS / 4)) * 4;
  const float* src = (m == 0) ? Wq : ((m == 1) ? Wk : Wv);
  const float  sc  = (m == 0) ? QSCALE : 1.0f;
  float4 v = *reinterpret_cast<const float4*>(src + off);
  bf16x4 o;
  o[0] = (bf16)(v.x * sc); o[1] = (bf16)(v.y * sc);
  o[2] = (bf16)(v.z * sc); o[3] = (bf16)(v.w * sc);
  *reinterpret_cast<bf16x4*>(Wb + (size_t)m * WELEMS + off) = o;
}

// ---------------------------------------------------------------------------
// Projection: Y = X @ W^T for all 3 W. 256 blocks x 512 threads (2 waves/SIMD).
// 8 waves = 4 row-bands x 2 col-halves; each wave: 16 rows x 96 cols (6 tiles).
// X A-fragments straight from global; W staged via global_load_lds DMA into
// unpadded [192][32] bf16 (64B rows -> conflict-free ds_read_b128).
// ---------------------------------------------------------------------------
__global__ __launch_bounds__(512) void proj_kernel(
    const float* __restrict__ x, const bf16* __restrict__ Wb,
    bf16* __restrict__ Qs, bf16* __restrict__ Ks, bf16* __restrict__ Vt)
{
  __shared__ bf16 Ws[2][192][32];

  const int t    = threadIdx.x;
  const int lane = t & 63;
  const int w    = t >> 6;       // 0..7
  const int band = w >> 1;       // 0..3: rows [16*band, 16*band+16)
  const int half = w & 1;        // 0..1: n-tiles [6*half, 6*half+6)
  const int r    = lane & 15;
  const int g    = lane >> 4;
  const long long row0 = (long long)blockIdx.x * 64;

  f32x4 acc[6];
  #pragma unroll
  for (int i = 0; i < 6; ++i) acc[i] = f32x4{0.f, 0.f, 0.f, 0.f};

  // per-lane X source: row = row0 + band*16 + r, col chunk g*8
  const float* xsrc = x + (row0 + band * 16 + r) * EMBED + g * 8;
  // per-lane W DMA source pattern: 4 lanes per row, (lane&3)*8 col offset
  const bf16* wdma = Wb + (long long)(lane >> 2) * EMBED + (lane & 3) * 8;

  // stage W tile: wave w -> rows [16w,16w+16); waves 0-3 also [128+16w, +16)
  #define STAGE_W(k0, buf)                                                   \
    {                                                                        \
      gl_lds16(wdma + (long long)(16 * w) * EMBED + (k0),                    \
               &Ws[buf][16 * w][0]);                                         \
      if (w < 4)                                                             \
        gl_lds16(wdma + (long long)(128 + 16 * w) * EMBED + (k0),            \
                 &Ws[buf][128 + 16 * w][0]);                                 \
    }

  // prologue
  STAGE_W(0, 0);
  float4 xa = *reinterpret_cast<const float4*>(xsrc);
  float4 xb = *reinterpret_cast<const float4*>(xsrc + 4);
  __syncthreads();   // drains DMA

  int cur = 0;
  for (int kt = 0; kt < 24; ++kt) {
    float4 xa2, xb2;
    const bool pf = kt < 23;
    if (pf) {
      const int k0n = (kt + 1) * 32;
      STAGE_W(k0n, cur ^ 1);
      xa2 = *reinterpret_cast<const float4*>(xsrc + k0n);
      xb2 = *reinterpret_cast<const float4*>(xsrc + k0n + 4);
    }
    bf16x8 af;
    af[0]=(bf16)xa.x; af[1]=(bf16)xa.y; af[2]=(bf16)xa.z; af[3]=(bf16)xa.w;
    af[4]=(bf16)xb.x; af[5]=(bf16)xb.y; af[6]=(bf16)xb.z; af[7]=(bf16)xb.w;
    #pragma unroll
    for (int i = 0; i < 6; ++i) {
      const int n = half * 6 + i;
      bf16x8 bfrag = *reinterpret_cast<const bf16x8*>(&Ws[cur][n * 16 + r][g * 8]);
      acc[i] = mfma16(af, bfrag, acc[i]);
    }
    __syncthreads();
    if (pf) { xa = xa2; xb = xb2; }
    cur ^= 1;
  }
  #undef STAGE_W

  // epilogue: 16x16 D layout row=(g*4+j), col=r. Tiles: 0-3 Q, 4-7 K, 8-11 V.
  const long long rowbase = row0 + band * 16 + g * 4;
  const int bb = (int)(rowbase >> 12);
  const int ss = (int)(rowbase & 4095);
  #pragma unroll
  for (int i = 0; i < 6; ++i) {
    const int gt = half * 6 + i;
    if (gt < 4) {
      #pragma unroll
      for (int j = 0; j < 4; ++j)
        Qs[(rowbase + j) * ADIM + gt * 16 + r] = (bf16)(acc[i][j]);
    } else if (gt < 8) {
      #pragma unroll
      for (int j = 0; j < 4; ++j)
        Ks[(rowbase + j) * ADIM + (gt - 4) * 16 + r] = (bf16)(acc[i][j]);
    } else {
      const int d = (gt - 8) * 16 + r;
      bf16x4 pack;
      pack[0] = (bf16)(acc[i][0]); pack[1] = (bf16)(acc[i][1]);
      pack[2] = (bf16)(acc[i][2]); pack[3] = (bf16)(acc[i][3]);
      *reinterpret_cast<bf16x4*>(&Vt[((long long)bb * 64 + d) * SEQ + ss]) = pack;
    }
  }
}

// ---------------------------------------------------------------------------
// Flash attention, causal. 32x32x16 MFMA, swapped operands: q = lane&31.
// 512 blocks x 8 waves; block owns one 32-row q-tile; waves kv-split stride 8.
// Pairing: blocks bi and bi+256 (same CU under round-robin XCD dispatch)
// carry complementary tiles qt and 127-qt  -> per-CU load balanced.
// ---------------------------------------------------------------------------
__global__ __launch_bounds__(512, 4) void attn_kernel(
    const bf16* __restrict__ Qs, const bf16* __restrict__ Ks,
    const bf16* __restrict__ Vt, float* __restrict__ out)
{
  __shared__ float Olds[8][32][68];
  __shared__ float Mlds[8][32];
  __shared__ float Llds[8][32];

  const int t    = threadIdx.x;
  const int lane = t & 63;
  const int w    = t >> 6;
  const int q    = lane & 31;
  const int h    = lane >> 5;
  const int bi   = blockIdx.x;
  int b, qt;
  if (bi < 256) { b = bi >> 7;               qt = bi & 127; }
  else          { b = 2 + ((bi - 256) >> 7); qt = 127 - (bi & 127); }
  const int qb = qt * 32;

  const bf16* Qb = Qs + (long long)b * SEQ * ADIM;
  const bf16* Kb = Ks + (long long)b * SEQ * ADIM;
  const bf16* Vb = Vt + (long long)b * ADIM * SEQ;

  // Q as B-operand: lane(q,h) holds Q[qb+q][kc*16 + h*8 + e]
  bf16x8 qf[4];
  #pragma unroll
  for (int kc = 0; kc < 4; ++kc)
    qf[kc] = *reinterpret_cast<const bf16x8*>(Qb + (qb + q) * ADIM + kc * 16 + h * 8);

  f32x16 o0 = {0,0,0,0,0,0,0,0,0,0,0,0,0,0,0,0};
  f32x16 o1 = {0,0,0,0,0,0,0,0,0,0,0,0,0,0,0,0};
  float m = -INFINITY, l = 0.f;

  const bf16* krow  = Kb + q * ADIM + h * 8;
  const bf16* vrow0 = Vb + (long long)q * SEQ + h * 8;
  const bf16* vrow1 = Vb + (long long)(32 + q) * SEQ + h * 8;

  int st = w;
  bf16x8 kf[4];
  if (st <= qt) {
    #pragma unroll
    for (int kc = 0; kc < 4; ++kc)
      kf[kc] = *reinterpret_cast<const bf16x8*>(krow + st * 32 * ADIM + kc * 16);
  }

  for (; st <= qt; st += 8) {
    const int kv0 = st * 32;

    // V for this tile (in flight across QK + softmax)
    bf16x8 vf00 = *reinterpret_cast<const bf16x8*>(vrow0 + kv0);
    bf16x8 vf01 = *reinterpret_cast<const bf16x8*>(vrow0 + kv0 + 16);
    bf16x8 vf10 = *reinterpret_cast<const bf16x8*>(vrow1 + kv0);
    bf16x8 vf11 = *reinterpret_cast<const bf16x8*>(vrow1 + kv0 + 16);

    // S^T = K Q^T : lane(q,h) reg(i*4+j) = S[key=kv0+j+8i+4h][qb+q]
    f32x16 s = {0,0,0,0,0,0,0,0,0,0,0,0,0,0,0,0};
    __builtin_amdgcn_s_setprio(1);
    s = mfma32(kf[0], qf[0], s);
    s = mfma32(kf[1], qf[1], s);
    s = mfma32(kf[2], qf[2], s);
    s = mfma32(kf[3], qf[3], s);
    __builtin_amdgcn_s_setprio(0);

    // prefetch next K tile (in flight across softmax + PV)
    if (st + 8 <= qt) {
      #pragma unroll
      for (int kc = 0; kc < 4; ++kc)
        kf[kc] = *reinterpret_cast<const bf16x8*>(krow + (st + 8) * 32 * ADIM + kc * 16);
    }

    // causal mask — only the diagonal tile
    if (st == qt) {
      #pragma unroll
      for (int i = 0; i < 4; ++i)
        #pragma unroll
        for (int j = 0; j < 4; ++j)
          if (kv0 + j + 8 * i + 4 * h > qb + q) s[i * 4 + j] = -INFINITY;
    }

    // per-lane online softmax: 1 shuffle for max, 1 for sum
    float tm = s[0];
    #pragma unroll
    for (int rr = 1; rr < 16; ++rr) tm = fmaxf(tm, s[rr]);
    tm = fmaxf(tm, __shfl_xor(tm, 32));

    const bool skip = __all((m > -1e37f) && (tm <= m + 8.0f));  // defer-max
    float mne;
    if (skip) {
      mne = m;
    } else {
      const float mn = fmaxf(m, tm);
      mne = (mn == -INFINITY) ? 0.f : mn;
      const float sc = exp2f(m - mne);
      #pragma unroll
      for (int rr = 0; rr < 16; ++rr) { o0[rr] *= sc; o1[rr] *= sc; }
      l *= sc;
      m = mn;
    }

    float rs = 0.f;
    #pragma unroll
    for (int rr = 0; rr < 16; ++rr) { s[rr] = exp2f(s[rr] - mne); rs += s[rr]; }
    rs += __shfl_xor(rs, 32);
    l += rs;

    // P^T fragments in-register, built in two halves (register relief):
    {
      unsigned a0 = cvtpk(s[0], s[1]), a1 = cvtpk(s[2], s[3]);
      unsigned b0 = cvtpk(s[4], s[5]), b1 = cvtpk(s[6], s[7]);
      unsigned a0x = __shfl_xor((int)a0, 32), a1x = __shfl_xor((int)a1, 32);
      unsigned b0x = __shfl_xor((int)b0, 32), b1x = __shfl_xor((int)b1, 32);
      union { unsigned u[4]; bf16x8 v; } pa0;
      pa0.u[0] = h ? b0x : a0;  pa0.u[1] = h ? b1x : a1;
      pa0.u[2] = h ? b0  : a0x; pa0.u[3] = h ? b1  : a1x;
      __builtin_amdgcn_s_setprio(1);
      o0 = mfma32(vf00, pa0.v, o0);
      o1 = mfma32(vf10, pa0.v, o1);
      __builtin_amdgcn_s_setprio(0);
    }
    {
      unsigned c0 = cvtpk(s[8],  s[9]),  c1 = cvtpk(s[10], s[11]);
      unsigned d0 = cvtpk(s[12], s[13]), d1 = cvtpk(s[14], s[15]);
      unsigned c0x = __shfl_xor((int)c0, 32), c1x = __shfl_xor((int)c1, 32);
      unsigned d0x = __shfl_xor((int)d0, 32), d1x = __shfl_xor((int)d1, 32);
      union { unsigned u[4]; bf16x8 v; } pa1;
      pa1.u[0] = h ? d0x : c0;  pa1.u[1] = h ? d1x : c1;
      pa1.u[2] = h ? d0  : c0x; pa1.u[3] = h ? d1  : c1x;
      __builtin_amdgcn_s_setprio(1);
      o0 = mfma32(vf01, pa1.v, o0);
      o1 = mfma32(vf11, pa1.v, o1);
      __builtin_amdgcn_s_setprio(0);
    }
  }

  // publish partials (C/D layout: d = dc*32 + 8*r2 + 4*h + j)
  #pragma unroll
  for (int r2 = 0; r2 < 4; ++r2) {
    f32x4 v0, v1;
    v0[0]=o0[r2*4+0]; v0[1]=o0[r2*4+1]; v0[2]=o0[r2*4+2]; v0[3]=o0[r2*4+3];
    v1[0]=o1[r2*4+0]; v1[1]=o1[r2*4+1]; v1[2]=o1[r2*4+2]; v1[3]=o1[r2*4+3];
    *reinterpret_cast<f32x4*>(&Olds[w][q][8 * r2 + 4 * h])      = v0;
    *reinterpret_cast<f32x4*>(&Olds[w][q][32 + 8 * r2 + 4 * h]) = v1;
  }
  if (h == 0) { Mlds[w][q] = m; Llds[w][q] = l; }
  __syncthreads();

  // combine 8 partials: thread -> (q=t>>4, 4 dims at (t&15)*4)
  {
    const int cq = t >> 4;
    const int cd = (t & 15) * 4;
    float mf = Mlds[0][cq];
    #pragma unroll
    for (int w2 = 1; w2 < 8; ++w2) mf = fmaxf(mf, Mlds[w2][cq]);
    float lf = 0.f;
    f32x4 ov = {0.f, 0.f, 0.f, 0.f};
    #pragma unroll
    for (int w2 = 0; w2 < 8; ++w2) {
      const float sc = exp2f(Mlds[w2][cq] - mf);
      lf += sc * Llds[w2][cq];
      const f32x4 pv = *reinterpret_cast<const f32x4*>(&Olds[w2][cq][cd]);
      ov[0] += sc * pv[0]; ov[1] += sc * pv[1];
      ov[2] += sc * pv[2]; ov[3] += sc * pv[3];
    }
    const float inv = 1.f / lf;
    float4 res;
    res.x = ov[0] * inv; res.y = ov[1] * inv;
    res.z = ov[2] * inv; res.w = ov[3] * inv;
    *reinterpret_cast<float4*>(out + ((long long)b * SEQ + qb + cq) * ADIM + cd) = res;
  }
}

extern "C" void kernel_launch(void* const* d_in, const int* in_sizes, int n_in,
                              void* d_out, int out_size, void* d_ws, size_t ws_size,
                              hipStream_t stream) {
  const float* x  = (const float*)d_in[0];
  const float* Wq = (const float*)d_in[1];
  const float* Wk = (const float*)d_in[2];
  const float* Wv = (const float*)d_in[3];

  const size_t qkvElems = (size_t)NBATCH * SEQ * ADIM;
  bf16* Qs = (bf16*)d_ws;
  bf16* Ks = Qs + qkvElems;
  bf16* Vt = Ks + qkvElems;
  bf16* Wb = Vt + qkvElems;

  wconv_kernel<<<3 * WELEMS / 4 / 256, 256, 0, stream>>>(Wq, Wk, Wv, Wb);
  proj_kernel<<<NBATCH * SEQ / 64, 512, 0, stream>>>(x, Wb, Qs, Ks, Vt);
  attn_kernel<<<512, 512, 0, stream>>>(Qs, Ks, Vt, (float*)d_out);
}